// Round 11
// baseline (667.285 us; speedup 1.0000x reference)
//
#include <hip/hip_runtime.h>
#include <hip/hip_bf16.h>

typedef __attribute__((ext_vector_type(8))) short bf16x8;
typedef __attribute__((ext_vector_type(4))) short short4v;
typedef __attribute__((ext_vector_type(4))) float f32x4;
typedef __attribute__((ext_vector_type(4))) float float4v;

#define NT 1024
#define NS 16
#define NSG 4
#define NGRP 4

constexpr int L0 = 360, L2n = 90, L3n = 45;
constexpr int SD = 67, NQ = 2278, LIB = 2480, FCIN = 2880;

constexpr int C1_CH = 20, C1_ROWS = 186, S1B = C1_ROWS * C1_CH * 2;  // 7440
constexpr int C2_CH = 44, C2_ROWS = 96, S2B = C2_ROWS * C2_CH * 2;   // 8448
constexpr int S3B = 5776;        // per-sample c3 stride
constexpr int XB_STRIDE = 392;   // bf16 lidar stage: [2 zero][360 data][2 zero][28 slack]

constexpr int OFF_C3 = 0;
constexpr int SZ_C3 = NS * S3B;             // 92416
constexpr int OFF_C1 = OFF_C3 + SZ_C3;      // 92416
constexpr int SZ_C1 = NSG * S1B;            // 29760
constexpr int OFF_C2 = OFF_C1 + SZ_C1;      // 122176
constexpr int SZ_C2 = NSG * S2B + 512;      // 34304
constexpr int OFF_XB = OFF_C2 + SZ_C2;      // 156480
constexpr int SZ_XB = NSG * XB_STRIDE * 2;  // 3136
constexpr int OFF_PAR = OFF_XB + SZ_XB;     // 159616 ; f32: b1[16] b2[32] b3[64] fcb[64]
constexpr int SMEM_BYTES = OFF_PAR + 704;   // 160320
static_assert(SMEM_BYTES <= 163840, "LDS over budget");

// aliases (region liveness verified per phase)
constexpr int OFF_STATE = OFF_C1;                    // [16][68] f32
constexpr int OFF_SBF = OFF_C1 + 16 * 68 * 4;        // [16][104] bf16 (state+const+pad)
constexpr int OFF_FCRED = OFF_C2;                    // [4][4][16][17] f32
constexpr int OFF_Y = OFF_C2;                        // [3][16][84] f32 (aliases red, after)

// workspace layout (bytes)
constexpr size_t WSO_FCW = 0;                           // [64][2880] bf16, m'=t*64+o
constexpr size_t WSO_W2F = WSO_FCW + 64 * FCIN * 2;     // 368640: [3][32][32] bf16
constexpr size_t WSO_W3F = WSO_W2F + 3 * 32 * 32 * 2;   // 374784: [5][64][32] bf16
constexpr size_t WSO_UB  = WSO_W3F + 5 * 64 * 32 * 2;   // 395264: [3][80][96] bf16 sym-folded
constexpr size_t WSO_W1F = WSO_UB + 3 * 80 * 96 * 2;    // 441344: [16][32] bf16
constexpr size_t WS_NEED = WSO_W1F + 16 * 32 * 2;       // 442368

__device__ __forceinline__ short f2b(float f) {
    return (short)__builtin_bit_cast(unsigned short, __float2bfloat16(f));
}
__device__ __forceinline__ bf16x8 ld_frag8(const char* p) {   // 8B-aligned LDS, 2x ds_read_b64
    union { bf16x8 v; short4v h[2]; } u;
    u.h[0] = *(const short4v*)(p);
    u.h[1] = *(const short4v*)(p + 8);
    return u.v;
}
__device__ __forceinline__ int2 qab_of(int q) {
    float qf = (float)q;
    int a = (int)((135.0f - sqrtf(135.0f * 135.0f - 8.0f * qf)) * 0.5f);
    a = a < 0 ? 0 : (a > 66 ? 66 : a);
    while (a > 0 && (a * 67 - (a * (a - 1)) / 2) > q) --a;
    while (a < 66 && ((a + 1) * 67 - ((a + 1) * a) / 2) <= q) ++a;
    int b = a + (q - (a * 67 - (a * (a - 1)) / 2));
    return make_int2(a, b);
}

__global__ __launch_bounds__(256) void pre_convert(
    const float* __restrict__ fcw, const float* __restrict__ w2,
    const float* __restrict__ w3, const float* __restrict__ w1,
    const float* __restrict__ sw, char* __restrict__ ws) {
    int idx = blockIdx.x * 256 + threadIdx.x;
    if (idx < 64 * FCIN) {
        int j = idx / FCIN, mp = idx % FCIN;
        int o = mp & 63, t = mp >> 6;
        ((short*)(ws + WSO_FCW))[idx] = f2b(fcw[j * FCIN + o * 45 + t]);
    }
    if (idx < 3 * 32 * 32) {
        int p = idx >> 10, o = (idx >> 5) & 31, k32 = idx & 31;
        int kk = 2 * p + (k32 >> 4), ic = k32 & 15;
        float v = (kk < 5) ? w2[(o * 16 + ic) * 5 + kk] : 0.f;
        ((short*)(ws + WSO_W2F))[idx] = f2b(v);
    }
    if (idx < 5 * 64 * 32) {
        int kk = idx >> 11, o = (idx >> 5) & 63, ic = idx & 31;
        ((short*)(ws + WSO_W3F))[idx] = f2b(w3[(o * 32 + ic) * 5 + kk]);
    }
    if (idx < 3 * 80 * 96) {   // symmetric-folded quad+linear+const matrix
        int r = idx / (80 * 96), rem = idx % (80 * 96), nn = rem / 96, kk = rem % 96;
        float v = 0.f;
        if (nn < 68 && kk < 68) {
            if (nn == 67 && kk == 67) v = sw[r * LIB];
            else if (nn == 67) v = 0.5f * sw[r * LIB + 1 + kk];
            else if (kk == 67) v = 0.5f * sw[r * LIB + 1 + nn];
            else {
                int a = nn < kk ? nn : kk, b = nn < kk ? kk : nn;
                int q = a * 67 - (a * (a - 1)) / 2 + (b - a);
                v = sw[r * LIB + 68 + q];
                if (nn != kk) v *= 0.5f;
            }
        }
        ((short*)(ws + WSO_UB))[idx] = f2b(v);
    }
    if (idx < 512) {           // conv1 A-fragment [16 o][32 k], taps 0..4 valid
        int o = idx >> 5, k = idx & 31;
        ((short*)(ws + WSO_W1F))[idx] = (k < 5) ? f2b(w1[o * 5 + k]) : (short)0;
    }
}

__global__ __launch_bounds__(NT, 4) void sindy_mfma(
    const float* __restrict__ lidar, const float* __restrict__ odom,
    const float* __restrict__ w1, const float* __restrict__ b1,
    const float* __restrict__ w2, const float* __restrict__ b2,
    const float* __restrict__ w3, const float* __restrict__ b3,
    const float* __restrict__ fcw, const float* __restrict__ fcb,
    const float* __restrict__ sw, const char* __restrict__ ws,
    float* __restrict__ out)
{
    __shared__ char smem[SMEM_BYTES];
    const int tid = threadIdx.x;
    const int wv = tid >> 6, lane = tid & 63;
    const int lr = lane & 15, lg = lane >> 4;
    const long blk = blockIdx.x;
    float* par = (float*)(smem + OFF_PAR);
    short* xb = (short*)(smem + OFF_XB);

    // ---- wave roles ----
    const int sW = wv & 3;              // sample-in-group
    const int qW = wv >> 2;             // conv1 t-quarter; conv2 t-portion; conv3 (op,th)
    const int op3 = qW & 1;             // conv3 o-pair
    const int th3 = qW >> 1;            // conv3 t-portion: 0 -> {0,1}, 1 -> {2}

    // ---- fc wave roles (needed early for prefetch) ----
    const int jt_fc = wv & 3, kq_fc = wv >> 2, j0_fc = jt_fc * 16;
    const short* fb = ws ? (const short*)(ws + WSO_FCW) + (long)(j0_fc + lr) * FCIN : nullptr;
    auto loadB = [&](int kt) -> bf16x8 {
        int k = kt * 32 + lg * 8;
        if (fb) return *(const bf16x8*)(fb + k);
        bf16x8 bv;
        #pragma unroll
        for (int e = 0; e < 8; e++) {
            int mp = k + e, o = mp & 63, t = mp >> 6;
            bv[e] = f2b(fcw[(long)(j0_fc + lr) * FCIN + o * 45 + t]);
        }
        return bv;
    };
    bf16x8 bvA, bvB;   // fc B prefetch registers

    // ---- only conv1 A-fragment is hoisted (4 VGPR) ----
    bf16x8 af1;
    if (ws) {
        af1 = *(const bf16x8*)(ws + WSO_W1F + (lr * 32 + lg * 8) * 2);
    } else {
        #pragma unroll
        for (int e = 0; e < 8; e++) { int k = lg * 8 + e; af1[e] = (k < 5) ? f2b(w1[lr * 5 + k]) : (short)0; }
    }

    // ---- bf16 lidar staging helper ----
    auto stage_xb = [&](int g) {
        float4v v = ((const float4v*)(lidar + (blk * NS + g * NSG) * L0))[tid];
        int si = tid / 90, c = tid % 90;
        short* dst = xb + si * XB_STRIDE + 2 + 4 * c;
        int p0 = (int)(unsigned short)f2b(v[0]) | ((int)(unsigned short)f2b(v[1]) << 16);
        int p1 = (int)(unsigned short)f2b(v[2]) | ((int)(unsigned short)f2b(v[3]) << 16);
        *(int*)(dst) = p0;
        *(int*)(dst + 2) = p1;
    };

    // ================= P0 =================
    if (tid < 16) par[tid] = b1[tid];
    else if (tid < 48) par[16 + tid - 16] = b2[tid - 16];
    else if (tid < 112) par[48 + tid - 48] = b3[tid - 48];
    else if (tid < 176) par[112 + tid - 112] = fcb[tid - 112];
    else if (tid < 184) {               // xb border zeros
        int s = (tid - 176) >> 1, h = (tid - 176) & 1;
        ((int*)xb)[s * (XB_STRIDE / 2) + (h ? 181 : 0)] = 0;
    }
    if (tid >= 448 && tid < 608) {      // c1 borders
        int i = tid - 448, slot = i / 40, r = i % 40;
        const int rows[4] = {2, 3, 184, 185};
        *(int*)(smem + OFF_C1 + slot * S1B + rows[r / 10] * (C1_CH * 2) + (r % 10) * 4) = 0;
    }
    if (tid >= 608 && tid < 960) {      // c2 borders
        int i = tid - 608, slot = i / 88, r = i % 88;
        const int rows[4] = {2, 3, 94, 95};
        *(int*)(smem + OFF_C2 + slot * S2B + rows[r / 22] * (C2_CH * 2) + (r % 22) * 4) = 0;
    }
    if (tid < 360) stage_xb(0);
    __syncthreads();

    // ---- hoisted biases (small scalars) ----
    float bia1_[4], bia2_[2][4], bia3_[2][4];
    #pragma unroll
    for (int r = 0; r < 4; r++) {
        bia1_[r] = par[lg * 4 + r];
        #pragma unroll
        for (int ot = 0; ot < 2; ot++) bia2_[ot][r] = par[16 + ot * 16 + lg * 4 + r];
        #pragma unroll
        for (int j = 0; j < 2; j++) bia3_[j][r] = par[48 + (op3 * 2 + j) * 16 + lg * 4 + r];
    }

    // ---- conv1 via MFMA (mapping unchanged from R9) ----
    auto conv1_body = [&]() {
        const short* xs = xb + sW * XB_STRIDE;
        char* c1s = smem + OFF_C1 + sW * S1B;
        #pragma unroll
        for (int i = 0; i < 3; ++i) {
            const int t = (qW * 3 + i) * 16 + lr;
            bf16x8 bv = {0, 0, 0, 0, 0, 0, 0, 0};
            if (lg == 0) {
                const short* xp = xs + 2 * t;
                int d0 = *(const int*)(xp);
                int d1 = *(const int*)(xp + 2);
                bv[0] = (short)(d0 & 0xffff); bv[1] = (short)(d0 >> 16);
                bv[2] = (short)(d1 & 0xffff); bv[3] = (short)(d1 >> 16);
                bv[4] = xp[4];
            }
            f32x4 acc = {0.f, 0.f, 0.f, 0.f};
            acc = __builtin_amdgcn_mfma_f32_16x16x32_bf16(af1, bv, acc, 0, 0, 0);
            if (t < 180) {
                short4v pk = { f2b(fmaxf(acc[0] + bia1_[0], 0.f)), f2b(fmaxf(acc[1] + bia1_[1], 0.f)),
                               f2b(fmaxf(acc[2] + bia1_[2], 0.f)), f2b(fmaxf(acc[3] + bia1_[3], 0.f)) };
                *(short4v*)(c1s + (t + 4) * (C1_CH * 2) + lg * 8) = pk;
            }
        }
    };

    conv1_body();                        // C1(g=0)
    __syncthreads();

    // ================= conv groups: {C2(g)+stage | C3(g)+C1(g+1)} =================
    for (int g = 0; g < NGRP; ++g) {
        // ---- C2: wave = (sW, t-portion); all 32 o per B-read. af2L lives here only ----
        {
            bf16x8 af2L[2][3];
            if (ws) {
                #pragma unroll
                for (int ot = 0; ot < 2; ot++)
                    #pragma unroll
                    for (int p = 0; p < 3; p++)
                        af2L[ot][p] = *(const bf16x8*)(ws + WSO_W2F + ((p * 32 + ot * 16 + lr) * 32 + lg * 8) * 2);
            } else {
                #pragma unroll
                for (int ot = 0; ot < 2; ot++)
                    #pragma unroll
                    for (int p = 0; p < 3; p++)
                        #pragma unroll
                        for (int e = 0; e < 8; e++) {
                            int k32 = lg * 8 + e, kk = 2 * p + (k32 >> 4), ic = k32 & 15;
                            af2L[ot][p][e] = (kk < 5) ? f2b(w2[((ot * 16 + lr) * 16 + ic) * 5 + kk]) : (short)0;
                        }
            }
            const int kkp = lane >> 5, i0 = (lg & 1) * 8;
            const char* bp = smem + OFF_C1 + sW * S1B
                           + (2 * lr + kkp + 2) * (C1_CH * 2) + i0 * 2;
            char* c2s = smem + OFF_C2 + sW * S2B;
            const bool stg = (g < NGRP - 1) && (tid < 360);
            float4v lv;
            if (stg) lv = ((const float4v*)(lidar + (blk * NS + (g + 1) * NSG) * L0))[tid];

            const int tbase = (qW < 2) ? qW * 2 : (2 + qW);   // 0,2,4,5
            const int nT = (qW < 2) ? 2 : 1;
            for (int it = 0; it < nT; ++it) {
                const int T = tbase + it;
                f32x4 a0 = {0.f, 0.f, 0.f, 0.f}, a1 = {0.f, 0.f, 0.f, 0.f};
                #pragma unroll
                for (int p = 0; p < 3; p++) {
                    bf16x8 bf = ld_frag8(bp + T * 1280 + p * 80);
                    a0 = __builtin_amdgcn_mfma_f32_16x16x32_bf16(af2L[0][p], bf, a0, 0, 0, 0);
                    a1 = __builtin_amdgcn_mfma_f32_16x16x32_bf16(af2L[1][p], bf, a1, 0, 0, 0);
                }
                const int tw = T * 16 + lr;
                if (tw < L2n) {
                    short4v pk0 = { f2b(fmaxf(a0[0] + bia2_[0][0], 0.f)), f2b(fmaxf(a0[1] + bia2_[0][1], 0.f)),
                                    f2b(fmaxf(a0[2] + bia2_[0][2], 0.f)), f2b(fmaxf(a0[3] + bia2_[0][3], 0.f)) };
                    short4v pk1 = { f2b(fmaxf(a1[0] + bia2_[1][0], 0.f)), f2b(fmaxf(a1[1] + bia2_[1][1], 0.f)),
                                    f2b(fmaxf(a1[2] + bia2_[1][2], 0.f)), f2b(fmaxf(a1[3] + bia2_[1][3], 0.f)) };
                    char* wp = c2s + (tw + 4) * (C2_CH * 2);
                    *(short4v*)(wp + lg * 8) = pk0;
                    *(short4v*)(wp + 32 + lg * 8) = pk1;
                }
            }
            if (stg) {
                int si = tid / 90, c = tid % 90;
                short* dst = xb + si * XB_STRIDE + 2 + 4 * c;
                int p0 = (int)(unsigned short)f2b(lv[0]) | ((int)(unsigned short)f2b(lv[1]) << 16);
                int p1 = (int)(unsigned short)f2b(lv[2]) | ((int)(unsigned short)f2b(lv[3]) << 16);
                *(int*)(dst) = p0;
                *(int*)(dst + 2) = p1;
            }
        }
        __syncthreads();

        // ---- C3: wave = (sW, op3, th3); 32 o per B-read. af3L lives here only ----
        {
            bf16x8 af3L[2][5];
            if (ws) {
                #pragma unroll
                for (int j = 0; j < 2; j++)
                    #pragma unroll
                    for (int kk = 0; kk < 5; kk++)
                        af3L[j][kk] = *(const bf16x8*)(ws + WSO_W3F + ((kk * 64 + (op3 * 2 + j) * 16 + lr) * 32 + lg * 8) * 2);
            } else {
                #pragma unroll
                for (int j = 0; j < 2; j++)
                    #pragma unroll
                    for (int kk = 0; kk < 5; kk++)
                        #pragma unroll
                        for (int e = 0; e < 8; e++)
                            af3L[j][kk][e] = f2b(w3[(((op3 * 2 + j) * 16 + lr) * 32 + lg * 8 + e) * 5 + kk]);
            }
            const char* bp2 = smem + OFF_C2 + sW * S2B
                            + (2 * lr + 2) * (C2_CH * 2) + lg * 16;
            char* c3s = smem + OFF_C3 + (g * NSG + sW) * S3B;
            const int ttbase = (th3 == 0) ? 0 : 2;
            const int nT3 = (th3 == 0) ? 2 : 1;
            for (int it = 0; it < nT3; ++it) {
                const int tt = ttbase + it;
                f32x4 a0 = {0.f, 0.f, 0.f, 0.f}, a1 = {0.f, 0.f, 0.f, 0.f};
                #pragma unroll
                for (int kk = 0; kk < 5; kk++) {
                    bf16x8 bf = ld_frag8(bp2 + tt * 2816 + kk * 88);
                    a0 = __builtin_amdgcn_mfma_f32_16x16x32_bf16(af3L[0][kk], bf, a0, 0, 0, 0);
                    a1 = __builtin_amdgcn_mfma_f32_16x16x32_bf16(af3L[1][kk], bf, a1, 0, 0, 0);
                }
                const int tw = tt * 16 + lr;
                if (tw < L3n) {
                    short4v pk0 = { f2b(fmaxf(a0[0] + bia3_[0][0], 0.f)), f2b(fmaxf(a0[1] + bia3_[0][1], 0.f)),
                                    f2b(fmaxf(a0[2] + bia3_[0][2], 0.f)), f2b(fmaxf(a0[3] + bia3_[0][3], 0.f)) };
                    short4v pk1 = { f2b(fmaxf(a1[0] + bia3_[1][0], 0.f)), f2b(fmaxf(a1[1] + bia3_[1][1], 0.f)),
                                    f2b(fmaxf(a1[2] + bia3_[1][2], 0.f)), f2b(fmaxf(a1[3] + bia3_[1][3], 0.f)) };
                    const int orow0 = op3 * 32 + lg * 4;
                    const int orow1 = op3 * 32 + 16 + lg * 4;
                    int bo0 = ((tw * 64 + orow0) * 2) ^ ((tw & 7) << 4);
                    int bo1 = ((tw * 64 + orow1) * 2) ^ ((tw & 7) << 4);
                    *(short4v*)(c3s + bo0) = pk0;
                    *(short4v*)(c3s + bo1) = pk1;
                }
            }
            if (g < NGRP - 1) conv1_body();
            else { bvA = loadB(kq_fc); bvB = loadB(kq_fc + 4); }   // fc B prefetch across barrier
        }
        __syncthreads();
    }

    // ================= FC: M=16, N=64, K=2880 ; wave = (j-tile, k-quarter) =================
    {
        const int nI = (kq_fc < 2) ? 23 : 22;
        const char* abase = smem + OFF_C3 + lr * S3B;
        auto loadA = [&](int kt) -> bf16x8 {
            int k = kt * 32 + lg * 8;
            int bo = (k * 2) ^ (((k >> 6) & 7) << 4);
            return *(const bf16x8*)(abase + bo);
        };
        f32x4 accA = {0.f, 0.f, 0.f, 0.f}, accB = {0.f, 0.f, 0.f, 0.f};
        int kt = kq_fc;
        bf16x8 bv0 = bvA, bv1 = bvB;
        int i = 0;
        for (; i + 1 < nI; i += 2) {
            bf16x8 cur0 = bv0; bv0 = bv1;
            if (i + 2 < nI) bv1 = loadB(kt + 8);
            accA = __builtin_amdgcn_mfma_f32_16x16x32_bf16(loadA(kt), cur0, accA, 0, 0, 0);
            kt += 4;
            bf16x8 cur1 = bv0; bv0 = bv1;
            if (i + 3 < nI) bv1 = loadB(kt + 8);
            accB = __builtin_amdgcn_mfma_f32_16x16x32_bf16(loadA(kt), cur1, accB, 0, 0, 0);
            kt += 4;
        }
        if (i < nI)
            accA = __builtin_amdgcn_mfma_f32_16x16x32_bf16(loadA(kt), bv0, accA, 0, 0, 0);
        f32x4 acc = accA + accB;
        float* red = (float*)(smem + OFF_FCRED);
        #pragma unroll
        for (int r = 0; r < 4; r++)
            red[((jt_fc * 4 + kq_fc) * 16 + lg * 4 + r) * 17 + lr] = acc[r];
    }
    __syncthreads();

    // ================= fc-reduce (wave = sample) + trig partials =================
    const int s = wv;
    const long n = blk * NS + s;
    float* red = (float*)(smem + OFF_FCRED);
    float* strow = (float*)(smem + OFF_STATE) + s * 68;
    short* sbrow = (short*)(smem + OFF_SBF) + s * 104;
    float ts0, ts1, ts2;
    {
        int jt = lane >> 4, col = lane & 15;
        float v = red[((jt * 4 + 0) * 16 + s) * 17 + col]
                + red[((jt * 4 + 1) * 16 + s) * 17 + col]
                + red[((jt * 4 + 2) * 16 + s) * 17 + col]
                + red[((jt * 4 + 3) * 16 + s) * 17 + col]
                + par[112 + lane];
        strow[lane] = v;
        if (ws) sbrow[lane] = f2b(v);
        float sn = __sinf(v), cs = __cosf(v);
        ts0 = sw[2346 + lane] * sn + sw[2413 + lane] * cs;
        ts1 = sw[LIB + 2346 + lane] * sn + sw[LIB + 2413 + lane] * cs;
        ts2 = sw[2 * LIB + 2346 + lane] * sn + sw[2 * LIB + 2413 + lane] * cs;
        if (lane < 3) {
            float ov = odom[n * 3 + lane];
            strow[64 + lane] = ov;
            if (ws) sbrow[64 + lane] = f2b(ov);
            float sn2 = __sinf(ov), cs2 = __cosf(ov);
            int j2 = 64 + lane;
            ts0 += sw[2346 + j2] * sn2 + sw[2413 + j2] * cs2;
            ts1 += sw[LIB + 2346 + j2] * sn2 + sw[LIB + 2413 + j2] * cs2;
            ts2 += sw[2 * LIB + 2346 + j2] * sn2 + sw[2 * LIB + 2413 + j2] * cs2;
        }
        if (ws) {
            if (lane == 3) sbrow[67] = (short)0x3F80;            // 1.0 bf16 (const column)
            if (lane >= 4 && lane < 40) sbrow[64 + lane] = 0;    // pad 68..103
        }
    }

    if (ws) {
        __syncthreads();
        // ---- quad GEMM: Y_r = S * Ub_r^T ; 15 waves = (r, n-tile) ----
        if (wv < 15) {
            const int r = wv / 5, nt = wv % 5;
            const char* ubp = ws + WSO_UB + (size_t)(r * 80 + nt * 16 + lr) * 96 * 2;
            const char* sb = smem + OFF_SBF;
            f32x4 acc = {0.f, 0.f, 0.f, 0.f};
            #pragma unroll
            for (int kt = 0; kt < 3; ++kt) {
                bf16x8 av = ld_frag8(sb + lr * 208 + (kt * 32 + lg * 8) * 2);
                bf16x8 bv = *(const bf16x8*)(ubp + (kt * 32 + lg * 8) * 2);
                acc = __builtin_amdgcn_mfma_f32_16x16x32_bf16(av, bv, acc, 0, 0, 0);
            }
            float* Y = (float*)(smem + OFF_Y);
            #pragma unroll
            for (int rr = 0; rr < 4; ++rr)
                Y[(r * 16 + lg * 4 + rr) * 84 + nt * 16 + lr] = acc[rr];
        }
        __syncthreads();
        // ---- dot(S, Y_r) + trig partials -> out ----
        const float* Y = (const float*)(smem + OFF_Y);
        float sj = strow[lane];
        float d0 = Y[(0 * 16 + s) * 84 + lane] * sj + ts0;
        float d1 = Y[(1 * 16 + s) * 84 + lane] * sj + ts1;
        float d2 = Y[(2 * 16 + s) * 84 + lane] * sj + ts2;
        if (lane < 4) {
            int j = 64 + lane;
            float sj2 = (lane < 3) ? strow[j] : 1.0f;
            d0 += Y[(0 * 16 + s) * 84 + j] * sj2;
            d1 += Y[(1 * 16 + s) * 84 + j] * sj2;
            d2 += Y[(2 * 16 + s) * 84 + j] * sj2;
        }
        #pragma unroll
        for (int off = 32; off; off >>= 1) {
            d0 += __shfl_xor(d0, off, 64);
            d1 += __shfl_xor(d1, off, 64);
            d2 += __shfl_xor(d2, off, 64);
        }
        if (lane == 0) {
            out[n * 3 + 0] = strow[64] + 0.1f * d0;
            out[n * 3 + 1] = strow[65] + 0.1f * d1;
            out[n * 3 + 2] = strow[66] + 0.1f * d2;
        }
    } else {
        // ---- fallback scalar tail (no ws) ----
        for (int i2 = lane; i2 < SD; i2 += 64) {
            float sv = strow[i2];
            ts0 += sw[1 + i2] * sv; ts1 += sw[LIB + 1 + i2] * sv; ts2 += sw[2 * LIB + 1 + i2] * sv;
        }
        if (lane == 0) { ts0 += sw[0]; ts1 += sw[LIB]; ts2 += sw[2 * LIB]; }
        for (int q = lane; q < NQ; q += 64) {
            int2 ab = qab_of(q);
            float p = strow[ab.x] * strow[ab.y];
            ts0 += sw[68 + q] * p; ts1 += sw[LIB + 68 + q] * p; ts2 += sw[2 * LIB + 68 + q] * p;
        }
        #pragma unroll
        for (int off = 32; off; off >>= 1) {
            ts0 += __shfl_xor(ts0, off, 64);
            ts1 += __shfl_xor(ts1, off, 64);
            ts2 += __shfl_xor(ts2, off, 64);
        }
        if (lane == 0) {
            out[n * 3 + 0] = strow[64] + 0.1f * ts0;
            out[n * 3 + 1] = strow[65] + 0.1f * ts1;
            out[n * 3 + 2] = strow[66] + 0.1f * ts2;
        }
    }
}

extern "C" void kernel_launch(void* const* d_in, const int* in_sizes, int n_in,
                              void* d_out, int out_size, void* d_ws, size_t ws_size,
                              hipStream_t stream) {
    const float* lidar = (const float*)d_in[0];
    const float* odom  = (const float*)d_in[1];
    const float* w1    = (const float*)d_in[2];
    const float* b1    = (const float*)d_in[3];
    const float* w2    = (const float*)d_in[4];
    const float* b2    = (const float*)d_in[5];
    const float* w3    = (const float*)d_in[6];
    const float* b3    = (const float*)d_in[7];
    const float* fcw   = (const float*)d_in[8];
    const float* fcb   = (const float*)d_in[9];
    const float* sw    = (const float*)d_in[10];
    float* out = (float*)d_out;

    int B = in_sizes[0] / L0;          // 32768
    int blocks = B / NS;               // 2048

    char* ws = nullptr;
    if (ws_size >= WS_NEED) {
        ws = (char*)d_ws;
        pre_convert<<<(64 * FCIN + 255) / 256, 256, 0, stream>>>(fcw, w2, w3, w1, sw, ws);
    }
    sindy_mfma<<<blocks, NT, 0, stream>>>(lidar, odom, w1, b1, w2, b2, w3, b3,
                                          fcw, fcb, sw, ws, out);
}

// Round 12
// 664.672 us; speedup vs baseline: 1.0039x; 1.0039x over previous
//
#include <hip/hip_runtime.h>
#include <hip/hip_bf16.h>

typedef __attribute__((ext_vector_type(8))) short bf16x8;
typedef __attribute__((ext_vector_type(4))) short short4v;
typedef __attribute__((ext_vector_type(4))) float f32x4;
typedef __attribute__((ext_vector_type(4))) float float4v;

#define NT 1024
#define NS 16
#define NSG 4
#define NGRP 4

constexpr int L0 = 360, L2n = 90, L3n = 45;
constexpr int SD = 67, NQ = 2278, LIB = 2480, FCIN = 2880;

constexpr int C1_CH = 20, C1_ROWS = 186, S1B = C1_ROWS * C1_CH * 2;  // 7440
constexpr int C2_CH = 44, C2_ROWS = 96, S2B = C2_ROWS * C2_CH * 2;   // 8448
constexpr int S3B = 5776;        // per-sample c3 stride
constexpr int XB_STRIDE = 392;   // bf16 lidar stage: [2 zero][360 data][2 zero][28 slack]

constexpr int OFF_C3 = 0;
constexpr int SZ_C3 = NS * S3B;             // 92416
constexpr int OFF_C1 = OFF_C3 + SZ_C3;      // 92416
constexpr int SZ_C1 = NSG * S1B;            // 29760
constexpr int OFF_C2 = OFF_C1 + SZ_C1;      // 122176
constexpr int SZ_C2 = NSG * S2B + 512;      // 34304
constexpr int OFF_XB = OFF_C2 + SZ_C2;      // 156480
constexpr int SZ_XB = NSG * XB_STRIDE * 2;  // 3136
constexpr int OFF_PAR = OFF_XB + SZ_XB;     // 159616 ; f32: b1[16] b2[32] b3[64] fcb[64]
constexpr int SMEM_BYTES = OFF_PAR + 704;   // 160320
static_assert(SMEM_BYTES <= 163840, "LDS over budget");

// aliases (region liveness verified per phase)
constexpr int OFF_STATE = OFF_C1;                    // [16][68] f32
constexpr int OFF_SBF = OFF_C1 + 16 * 68 * 4;        // [16][104] bf16 (state+const+pad)
constexpr int OFF_FCRED = OFF_C2;                    // [4][4][16][17] f32
constexpr int OFF_Y = OFF_C2;                        // [3][16][84] f32 (aliases red, after)

// workspace layout (bytes)
constexpr size_t WSO_FCW = 0;                           // [64][2880] bf16, m'=t*64+o
constexpr size_t WSO_W2F = WSO_FCW + 64 * FCIN * 2;     // 368640: [3][32][32] bf16
constexpr size_t WSO_W3F = WSO_W2F + 3 * 32 * 32 * 2;   // 374784: [5][64][32] bf16
constexpr size_t WSO_UB  = WSO_W3F + 5 * 64 * 32 * 2;   // 395264: [3][80][96] bf16 sym-folded
constexpr size_t WSO_W1F = WSO_UB + 3 * 80 * 96 * 2;    // 441344: [16][32] bf16
constexpr size_t WS_NEED = WSO_W1F + 16 * 32 * 2;       // 442368

__device__ __forceinline__ short f2b(float f) {
    return (short)__builtin_bit_cast(unsigned short, __float2bfloat16(f));
}
__device__ __forceinline__ bf16x8 ld_frag8(const char* p) {   // 8B-aligned LDS, 2x ds_read_b64
    union { bf16x8 v; short4v h[2]; } u;
    u.h[0] = *(const short4v*)(p);
    u.h[1] = *(const short4v*)(p + 8);
    return u.v;
}
__device__ __forceinline__ int2 qab_of(int q) {
    float qf = (float)q;
    int a = (int)((135.0f - sqrtf(135.0f * 135.0f - 8.0f * qf)) * 0.5f);
    a = a < 0 ? 0 : (a > 66 ? 66 : a);
    while (a > 0 && (a * 67 - (a * (a - 1)) / 2) > q) --a;
    while (a < 66 && ((a + 1) * 67 - ((a + 1) * a) / 2) <= q) ++a;
    int b = a + (q - (a * 67 - (a * (a - 1)) / 2));
    return make_int2(a, b);
}

__global__ __launch_bounds__(256) void pre_convert(
    const float* __restrict__ fcw, const float* __restrict__ w2,
    const float* __restrict__ w3, const float* __restrict__ w1,
    const float* __restrict__ sw, char* __restrict__ ws) {
    int idx = blockIdx.x * 256 + threadIdx.x;
    if (idx < 64 * FCIN) {
        int j = idx / FCIN, mp = idx % FCIN;
        int o = mp & 63, t = mp >> 6;
        ((short*)(ws + WSO_FCW))[idx] = f2b(fcw[j * FCIN + o * 45 + t]);
    }
    if (idx < 3 * 32 * 32) {
        int p = idx >> 10, o = (idx >> 5) & 31, k32 = idx & 31;
        int kk = 2 * p + (k32 >> 4), ic = k32 & 15;
        float v = (kk < 5) ? w2[(o * 16 + ic) * 5 + kk] : 0.f;
        ((short*)(ws + WSO_W2F))[idx] = f2b(v);
    }
    if (idx < 5 * 64 * 32) {
        int kk = idx >> 11, o = (idx >> 5) & 63, ic = idx & 31;
        ((short*)(ws + WSO_W3F))[idx] = f2b(w3[(o * 32 + ic) * 5 + kk]);
    }
    if (idx < 3 * 80 * 96) {   // symmetric-folded quad+linear+const matrix
        int r = idx / (80 * 96), rem = idx % (80 * 96), nn = rem / 96, kk = rem % 96;
        float v = 0.f;
        if (nn < 68 && kk < 68) {
            if (nn == 67 && kk == 67) v = sw[r * LIB];
            else if (nn == 67) v = 0.5f * sw[r * LIB + 1 + kk];
            else if (kk == 67) v = 0.5f * sw[r * LIB + 1 + nn];
            else {
                int a = nn < kk ? nn : kk, b = nn < kk ? kk : nn;
                int q = a * 67 - (a * (a - 1)) / 2 + (b - a);
                v = sw[r * LIB + 68 + q];
                if (nn != kk) v *= 0.5f;
            }
        }
        ((short*)(ws + WSO_UB))[idx] = f2b(v);
    }
    if (idx < 512) {           // conv1 A-fragment [16 o][32 k], taps 0..4 valid
        int o = idx >> 5, k = idx & 31;
        ((short*)(ws + WSO_W1F))[idx] = (k < 5) ? f2b(w1[o * 5 + k]) : (short)0;
    }
}

// NOTE: second launch_bounds arg = 1 (min blocks/CU). LDS (160 KB) limits us to
// 1 block/CU anyway; declaring 4 forced a ~64-VGPR cap and caused scratch spills
// (R10/R11: FETCH 0.8 GB). With 1, the VGPR budget is 512/wave; the ~110-VGPR
// working set stays in registers.
__global__ __launch_bounds__(NT, 1) void sindy_mfma(
    const float* __restrict__ lidar, const float* __restrict__ odom,
    const float* __restrict__ w1, const float* __restrict__ b1,
    const float* __restrict__ w2, const float* __restrict__ b2,
    const float* __restrict__ w3, const float* __restrict__ b3,
    const float* __restrict__ fcw, const float* __restrict__ fcb,
    const float* __restrict__ sw, const char* __restrict__ ws,
    float* __restrict__ out)
{
    __shared__ char smem[SMEM_BYTES];
    const int tid = threadIdx.x;
    const int wv = tid >> 6, lane = tid & 63;
    const int lr = lane & 15, lg = lane >> 4;
    const long blk = blockIdx.x;
    float* par = (float*)(smem + OFF_PAR);
    short* xb = (short*)(smem + OFF_XB);

    // ---- wave roles ----
    const int sW = wv & 3;              // sample-in-group
    const int qW = wv >> 2;             // conv1 t-quarter; conv2 t-portion; conv3 (op,th)
    const int op3 = qW & 1;             // conv3 o-pair
    const int th3 = qW >> 1;            // conv3 t-portion: 0 -> {0,1}, 1 -> {2}

    // ---- fc wave roles (needed early for prefetch) ----
    const int jt_fc = wv & 3, kq_fc = wv >> 2, j0_fc = jt_fc * 16;
    const short* fb = ws ? (const short*)(ws + WSO_FCW) + (long)(j0_fc + lr) * FCIN : nullptr;
    auto loadB = [&](int kt) -> bf16x8 {
        int k = kt * 32 + lg * 8;
        if (fb) return *(const bf16x8*)(fb + k);
        bf16x8 bv;
        #pragma unroll
        for (int e = 0; e < 8; e++) {
            int mp = k + e, o = mp & 63, t = mp >> 6;
            bv[e] = f2b(fcw[(long)(j0_fc + lr) * FCIN + o * 45 + t]);
        }
        return bv;
    };
    bf16x8 bvA, bvB;   // fc B prefetch registers

    // ---- only conv1 A-fragment is hoisted (4 VGPR) ----
    bf16x8 af1;
    if (ws) {
        af1 = *(const bf16x8*)(ws + WSO_W1F + (lr * 32 + lg * 8) * 2);
    } else {
        #pragma unroll
        for (int e = 0; e < 8; e++) { int k = lg * 8 + e; af1[e] = (k < 5) ? f2b(w1[lr * 5 + k]) : (short)0; }
    }

    // ---- bf16 lidar staging helper ----
    auto stage_xb = [&](int g) {
        float4v v = ((const float4v*)(lidar + (blk * NS + g * NSG) * L0))[tid];
        int si = tid / 90, c = tid % 90;
        short* dst = xb + si * XB_STRIDE + 2 + 4 * c;
        int p0 = (int)(unsigned short)f2b(v[0]) | ((int)(unsigned short)f2b(v[1]) << 16);
        int p1 = (int)(unsigned short)f2b(v[2]) | ((int)(unsigned short)f2b(v[3]) << 16);
        *(int*)(dst) = p0;
        *(int*)(dst + 2) = p1;
    };

    // ================= P0 =================
    if (tid < 16) par[tid] = b1[tid];
    else if (tid < 48) par[16 + tid - 16] = b2[tid - 16];
    else if (tid < 112) par[48 + tid - 48] = b3[tid - 48];
    else if (tid < 176) par[112 + tid - 112] = fcb[tid - 112];
    else if (tid < 184) {               // xb border zeros
        int s = (tid - 176) >> 1, h = (tid - 176) & 1;
        ((int*)xb)[s * (XB_STRIDE / 2) + (h ? 181 : 0)] = 0;
    }
    if (tid >= 448 && tid < 608) {      // c1 borders
        int i = tid - 448, slot = i / 40, r = i % 40;
        const int rows[4] = {2, 3, 184, 185};
        *(int*)(smem + OFF_C1 + slot * S1B + rows[r / 10] * (C1_CH * 2) + (r % 10) * 4) = 0;
    }
    if (tid >= 608 && tid < 960) {      // c2 borders
        int i = tid - 608, slot = i / 88, r = i % 88;
        const int rows[4] = {2, 3, 94, 95};
        *(int*)(smem + OFF_C2 + slot * S2B + rows[r / 22] * (C2_CH * 2) + (r % 22) * 4) = 0;
    }
    if (tid < 360) stage_xb(0);
    __syncthreads();

    // ---- hoisted biases (small scalars) ----
    float bia1_[4], bia2_[2][4], bia3_[2][4];
    #pragma unroll
    for (int r = 0; r < 4; r++) {
        bia1_[r] = par[lg * 4 + r];
        #pragma unroll
        for (int ot = 0; ot < 2; ot++) bia2_[ot][r] = par[16 + ot * 16 + lg * 4 + r];
        #pragma unroll
        for (int j = 0; j < 2; j++) bia3_[j][r] = par[48 + (op3 * 2 + j) * 16 + lg * 4 + r];
    }

    // ---- conv1 via MFMA (mapping unchanged from R9) ----
    auto conv1_body = [&]() {
        const short* xs = xb + sW * XB_STRIDE;
        char* c1s = smem + OFF_C1 + sW * S1B;
        #pragma unroll
        for (int i = 0; i < 3; ++i) {
            const int t = (qW * 3 + i) * 16 + lr;
            bf16x8 bv = {0, 0, 0, 0, 0, 0, 0, 0};
            if (lg == 0) {
                const short* xp = xs + 2 * t;
                int d0 = *(const int*)(xp);
                int d1 = *(const int*)(xp + 2);
                bv[0] = (short)(d0 & 0xffff); bv[1] = (short)(d0 >> 16);
                bv[2] = (short)(d1 & 0xffff); bv[3] = (short)(d1 >> 16);
                bv[4] = xp[4];
            }
            f32x4 acc = {0.f, 0.f, 0.f, 0.f};
            acc = __builtin_amdgcn_mfma_f32_16x16x32_bf16(af1, bv, acc, 0, 0, 0);
            if (t < 180) {
                short4v pk = { f2b(fmaxf(acc[0] + bia1_[0], 0.f)), f2b(fmaxf(acc[1] + bia1_[1], 0.f)),
                               f2b(fmaxf(acc[2] + bia1_[2], 0.f)), f2b(fmaxf(acc[3] + bia1_[3], 0.f)) };
                *(short4v*)(c1s + (t + 4) * (C1_CH * 2) + lg * 8) = pk;
            }
        }
    };

    conv1_body();                        // C1(g=0)
    __syncthreads();

    // ================= conv groups: {C2(g)+stage | C3(g)+C1(g+1)} =================
    for (int g = 0; g < NGRP; ++g) {
        // ---- C2: wave = (sW, t-portion); all 32 o per B-read. af2L lives here only ----
        {
            bf16x8 af2L[2][3];
            if (ws) {
                #pragma unroll
                for (int ot = 0; ot < 2; ot++)
                    #pragma unroll
                    for (int p = 0; p < 3; p++)
                        af2L[ot][p] = *(const bf16x8*)(ws + WSO_W2F + ((p * 32 + ot * 16 + lr) * 32 + lg * 8) * 2);
            } else {
                #pragma unroll
                for (int ot = 0; ot < 2; ot++)
                    #pragma unroll
                    for (int p = 0; p < 3; p++)
                        #pragma unroll
                        for (int e = 0; e < 8; e++) {
                            int k32 = lg * 8 + e, kk = 2 * p + (k32 >> 4), ic = k32 & 15;
                            af2L[ot][p][e] = (kk < 5) ? f2b(w2[((ot * 16 + lr) * 16 + ic) * 5 + kk]) : (short)0;
                        }
            }
            const int kkp = lane >> 5, i0 = (lg & 1) * 8;
            const char* bp = smem + OFF_C1 + sW * S1B
                           + (2 * lr + kkp + 2) * (C1_CH * 2) + i0 * 2;
            char* c2s = smem + OFF_C2 + sW * S2B;
            const bool stg = (g < NGRP - 1) && (tid < 360);
            float4v lv;
            if (stg) lv = ((const float4v*)(lidar + (blk * NS + (g + 1) * NSG) * L0))[tid];

            const int tbase = (qW < 2) ? qW * 2 : (2 + qW);   // 0,2,4,5
            const int nT = (qW < 2) ? 2 : 1;
            for (int it = 0; it < nT; ++it) {
                const int T = tbase + it;
                f32x4 a0 = {0.f, 0.f, 0.f, 0.f}, a1 = {0.f, 0.f, 0.f, 0.f};
                #pragma unroll
                for (int p = 0; p < 3; p++) {
                    bf16x8 bf = ld_frag8(bp + T * 1280 + p * 80);
                    a0 = __builtin_amdgcn_mfma_f32_16x16x32_bf16(af2L[0][p], bf, a0, 0, 0, 0);
                    a1 = __builtin_amdgcn_mfma_f32_16x16x32_bf16(af2L[1][p], bf, a1, 0, 0, 0);
                }
                const int tw = T * 16 + lr;
                if (tw < L2n) {
                    short4v pk0 = { f2b(fmaxf(a0[0] + bia2_[0][0], 0.f)), f2b(fmaxf(a0[1] + bia2_[0][1], 0.f)),
                                    f2b(fmaxf(a0[2] + bia2_[0][2], 0.f)), f2b(fmaxf(a0[3] + bia2_[0][3], 0.f)) };
                    short4v pk1 = { f2b(fmaxf(a1[0] + bia2_[1][0], 0.f)), f2b(fmaxf(a1[1] + bia2_[1][1], 0.f)),
                                    f2b(fmaxf(a1[2] + bia2_[1][2], 0.f)), f2b(fmaxf(a1[3] + bia2_[1][3], 0.f)) };
                    char* wp = c2s + (tw + 4) * (C2_CH * 2);
                    *(short4v*)(wp + lg * 8) = pk0;
                    *(short4v*)(wp + 32 + lg * 8) = pk1;
                }
            }
            if (stg) {
                int si = tid / 90, c = tid % 90;
                short* dst = xb + si * XB_STRIDE + 2 + 4 * c;
                int p0 = (int)(unsigned short)f2b(lv[0]) | ((int)(unsigned short)f2b(lv[1]) << 16);
                int p1 = (int)(unsigned short)f2b(lv[2]) | ((int)(unsigned short)f2b(lv[3]) << 16);
                *(int*)(dst) = p0;
                *(int*)(dst + 2) = p1;
            }
        }
        __syncthreads();

        // ---- C3: wave = (sW, op3, th3); 32 o per B-read. af3L lives here only ----
        {
            bf16x8 af3L[2][5];
            if (ws) {
                #pragma unroll
                for (int j = 0; j < 2; j++)
                    #pragma unroll
                    for (int kk = 0; kk < 5; kk++)
                        af3L[j][kk] = *(const bf16x8*)(ws + WSO_W3F + ((kk * 64 + (op3 * 2 + j) * 16 + lr) * 32 + lg * 8) * 2);
            } else {
                #pragma unroll
                for (int j = 0; j < 2; j++)
                    #pragma unroll
                    for (int kk = 0; kk < 5; kk++)
                        #pragma unroll
                        for (int e = 0; e < 8; e++)
                            af3L[j][kk][e] = f2b(w3[(((op3 * 2 + j) * 16 + lr) * 32 + lg * 8 + e) * 5 + kk]);
            }
            const char* bp2 = smem + OFF_C2 + sW * S2B
                            + (2 * lr + 2) * (C2_CH * 2) + lg * 16;
            char* c3s = smem + OFF_C3 + (g * NSG + sW) * S3B;
            const int ttbase = (th3 == 0) ? 0 : 2;
            const int nT3 = (th3 == 0) ? 2 : 1;
            for (int it = 0; it < nT3; ++it) {
                const int tt = ttbase + it;
                f32x4 a0 = {0.f, 0.f, 0.f, 0.f}, a1 = {0.f, 0.f, 0.f, 0.f};
                #pragma unroll
                for (int kk = 0; kk < 5; kk++) {
                    bf16x8 bf = ld_frag8(bp2 + tt * 2816 + kk * 88);
                    a0 = __builtin_amdgcn_mfma_f32_16x16x32_bf16(af3L[0][kk], bf, a0, 0, 0, 0);
                    a1 = __builtin_amdgcn_mfma_f32_16x16x32_bf16(af3L[1][kk], bf, a1, 0, 0, 0);
                }
                const int tw = tt * 16 + lr;
                if (tw < L3n) {
                    short4v pk0 = { f2b(fmaxf(a0[0] + bia3_[0][0], 0.f)), f2b(fmaxf(a0[1] + bia3_[0][1], 0.f)),
                                    f2b(fmaxf(a0[2] + bia3_[0][2], 0.f)), f2b(fmaxf(a0[3] + bia3_[0][3], 0.f)) };
                    short4v pk1 = { f2b(fmaxf(a1[0] + bia3_[1][0], 0.f)), f2b(fmaxf(a1[1] + bia3_[1][1], 0.f)),
                                    f2b(fmaxf(a1[2] + bia3_[1][2], 0.f)), f2b(fmaxf(a1[3] + bia3_[1][3], 0.f)) };
                    const int orow0 = op3 * 32 + lg * 4;
                    const int orow1 = op3 * 32 + 16 + lg * 4;
                    int bo0 = ((tw * 64 + orow0) * 2) ^ ((tw & 7) << 4);
                    int bo1 = ((tw * 64 + orow1) * 2) ^ ((tw & 7) << 4);
                    *(short4v*)(c3s + bo0) = pk0;
                    *(short4v*)(c3s + bo1) = pk1;
                }
            }
            if (g < NGRP - 1) conv1_body();
            else { bvA = loadB(kq_fc); bvB = loadB(kq_fc + 4); }   // fc B prefetch across barrier
        }
        __syncthreads();
    }

    // ================= FC: M=16, N=64, K=2880 ; wave = (j-tile, k-quarter) =================
    {
        const int nI = (kq_fc < 2) ? 23 : 22;
        const char* abase = smem + OFF_C3 + lr * S3B;
        auto loadA = [&](int kt) -> bf16x8 {
            int k = kt * 32 + lg * 8;
            int bo = (k * 2) ^ (((k >> 6) & 7) << 4);
            return *(const bf16x8*)(abase + bo);
        };
        f32x4 accA = {0.f, 0.f, 0.f, 0.f}, accB = {0.f, 0.f, 0.f, 0.f};
        int kt = kq_fc;
        bf16x8 bv0 = bvA, bv1 = bvB;
        int i = 0;
        for (; i + 1 < nI; i += 2) {
            bf16x8 cur0 = bv0; bv0 = bv1;
            if (i + 2 < nI) bv1 = loadB(kt + 8);
            accA = __builtin_amdgcn_mfma_f32_16x16x32_bf16(loadA(kt), cur0, accA, 0, 0, 0);
            kt += 4;
            bf16x8 cur1 = bv0; bv0 = bv1;
            if (i + 3 < nI) bv1 = loadB(kt + 8);
            accB = __builtin_amdgcn_mfma_f32_16x16x32_bf16(loadA(kt), cur1, accB, 0, 0, 0);
            kt += 4;
        }
        if (i < nI)
            accA = __builtin_amdgcn_mfma_f32_16x16x32_bf16(loadA(kt), bv0, accA, 0, 0, 0);
        f32x4 acc = accA + accB;
        float* red = (float*)(smem + OFF_FCRED);
        #pragma unroll
        for (int r = 0; r < 4; r++)
            red[((jt_fc * 4 + kq_fc) * 16 + lg * 4 + r) * 17 + lr] = acc[r];
    }
    __syncthreads();

    // ================= fc-reduce (wave = sample) + trig partials =================
    const int s = wv;
    const long n = blk * NS + s;
    float* red = (float*)(smem + OFF_FCRED);
    float* strow = (float*)(smem + OFF_STATE) + s * 68;
    short* sbrow = (short*)(smem + OFF_SBF) + s * 104;
    float ts0, ts1, ts2;
    {
        int jt = lane >> 4, col = lane & 15;
        float v = red[((jt * 4 + 0) * 16 + s) * 17 + col]
                + red[((jt * 4 + 1) * 16 + s) * 17 + col]
                + red[((jt * 4 + 2) * 16 + s) * 17 + col]
                + red[((jt * 4 + 3) * 16 + s) * 17 + col]
                + par[112 + lane];
        strow[lane] = v;
        if (ws) sbrow[lane] = f2b(v);
        float sn = __sinf(v), cs = __cosf(v);
        ts0 = sw[2346 + lane] * sn + sw[2413 + lane] * cs;
        ts1 = sw[LIB + 2346 + lane] * sn + sw[LIB + 2413 + lane] * cs;
        ts2 = sw[2 * LIB + 2346 + lane] * sn + sw[2 * LIB + 2413 + lane] * cs;
        if (lane < 3) {
            float ov = odom[n * 3 + lane];
            strow[64 + lane] = ov;
            if (ws) sbrow[64 + lane] = f2b(ov);
            float sn2 = __sinf(ov), cs2 = __cosf(ov);
            int j2 = 64 + lane;
            ts0 += sw[2346 + j2] * sn2 + sw[2413 + j2] * cs2;
            ts1 += sw[LIB + 2346 + j2] * sn2 + sw[LIB + 2413 + j2] * cs2;
            ts2 += sw[2 * LIB + 2346 + j2] * sn2 + sw[2 * LIB + 2413 + j2] * cs2;
        }
        if (ws) {
            if (lane == 3) sbrow[67] = (short)0x3F80;            // 1.0 bf16 (const column)
            if (lane >= 4 && lane < 40) sbrow[64 + lane] = 0;    // pad 68..103
        }
    }

    if (ws) {
        __syncthreads();
        // ---- quad GEMM: Y_r = S * Ub_r^T ; 15 waves = (r, n-tile) ----
        if (wv < 15) {
            const int r = wv / 5, nt = wv % 5;
            const char* ubp = ws + WSO_UB + (size_t)(r * 80 + nt * 16 + lr) * 96 * 2;
            const char* sb = smem + OFF_SBF;
            f32x4 acc = {0.f, 0.f, 0.f, 0.f};
            #pragma unroll
            for (int kt = 0; kt < 3; ++kt) {
                bf16x8 av = ld_frag8(sb + lr * 208 + (kt * 32 + lg * 8) * 2);
                bf16x8 bv = *(const bf16x8*)(ubp + (kt * 32 + lg * 8) * 2);
                acc = __builtin_amdgcn_mfma_f32_16x16x32_bf16(av, bv, acc, 0, 0, 0);
            }
            float* Y = (float*)(smem + OFF_Y);
            #pragma unroll
            for (int rr = 0; rr < 4; ++rr)
                Y[(r * 16 + lg * 4 + rr) * 84 + nt * 16 + lr] = acc[rr];
        }
        __syncthreads();
        // ---- dot(S, Y_r) + trig partials -> out ----
        const float* Y = (const float*)(smem + OFF_Y);
        float sj = strow[lane];
        float d0 = Y[(0 * 16 + s) * 84 + lane] * sj + ts0;
        float d1 = Y[(1 * 16 + s) * 84 + lane] * sj + ts1;
        float d2 = Y[(2 * 16 + s) * 84 + lane] * sj + ts2;
        if (lane < 4) {
            int j = 64 + lane;
            float sj2 = (lane < 3) ? strow[j] : 1.0f;
            d0 += Y[(0 * 16 + s) * 84 + j] * sj2;
            d1 += Y[(1 * 16 + s) * 84 + j] * sj2;
            d2 += Y[(2 * 16 + s) * 84 + j] * sj2;
        }
        #pragma unroll
        for (int off = 32; off; off >>= 1) {
            d0 += __shfl_xor(d0, off, 64);
            d1 += __shfl_xor(d1, off, 64);
            d2 += __shfl_xor(d2, off, 64);
        }
        if (lane == 0) {
            out[n * 3 + 0] = strow[64] + 0.1f * d0;
            out[n * 3 + 1] = strow[65] + 0.1f * d1;
            out[n * 3 + 2] = strow[66] + 0.1f * d2;
        }
    } else {
        // ---- fallback scalar tail (no ws) ----
        for (int i2 = lane; i2 < SD; i2 += 64) {
            float sv = strow[i2];
            ts0 += sw[1 + i2] * sv; ts1 += sw[LIB + 1 + i2] * sv; ts2 += sw[2 * LIB + 1 + i2] * sv;
        }
        if (lane == 0) { ts0 += sw[0]; ts1 += sw[LIB]; ts2 += sw[2 * LIB]; }
        for (int q = lane; q < NQ; q += 64) {
            int2 ab = qab_of(q);
            float p = strow[ab.x] * strow[ab.y];
            ts0 += sw[68 + q] * p; ts1 += sw[LIB + 68 + q] * p; ts2 += sw[2 * LIB + 68 + q] * p;
        }
        #pragma unroll
        for (int off = 32; off; off >>= 1) {
            ts0 += __shfl_xor(ts0, off, 64);
            ts1 += __shfl_xor(ts1, off, 64);
            ts2 += __shfl_xor(ts2, off, 64);
        }
        if (lane == 0) {
            out[n * 3 + 0] = strow[64] + 0.1f * ts0;
            out[n * 3 + 1] = strow[65] + 0.1f * ts1;
            out[n * 3 + 2] = strow[66] + 0.1f * ts2;
        }
    }
}

extern "C" void kernel_launch(void* const* d_in, const int* in_sizes, int n_in,
                              void* d_out, int out_size, void* d_ws, size_t ws_size,
                              hipStream_t stream) {
    const float* lidar = (const float*)d_in[0];
    const float* odom  = (const float*)d_in[1];
    const float* w1    = (const float*)d_in[2];
    const float* b1    = (const float*)d_in[3];
    const float* w2    = (const float*)d_in[4];
    const float* b2    = (const float*)d_in[5];
    const float* w3    = (const float*)d_in[6];
    const float* b3    = (const float*)d_in[7];
    const float* fcw   = (const float*)d_in[8];
    const float* fcb   = (const float*)d_in[9];
    const float* sw    = (const float*)d_in[10];
    float* out = (float*)d_out;

    int B = in_sizes[0] / L0;          // 32768
    int blocks = B / NS;               // 2048

    char* ws = nullptr;
    if (ws_size >= WS_NEED) {
        ws = (char*)d_ws;
        pre_convert<<<(64 * FCIN + 255) / 256, 256, 0, stream>>>(fcw, w2, w3, w1, sw, ws);
    }
    sindy_mfma<<<blocks, NT, 0, stream>>>(lidar, odom, w1, b1, w2, b2, w3, b3,
                                          fcw, fcb, sw, ws, out);
}

// Round 13
// 234.738 us; speedup vs baseline: 2.8427x; 2.8316x over previous
//
#include <hip/hip_runtime.h>
#include <hip/hip_bf16.h>

typedef __attribute__((ext_vector_type(8))) short bf16x8;
typedef __attribute__((ext_vector_type(4))) short short4v;
typedef __attribute__((ext_vector_type(4))) float f32x4;
typedef __attribute__((ext_vector_type(4))) float float4v;

#define NT 1024
#define NS 16
#define NSG 4
#define NGRP 4

constexpr int L0 = 360, L2n = 90, L3n = 45;
constexpr int SD = 67, NQ = 2278, LIB = 2480, FCIN = 2880;

constexpr int C1_CH = 20, C1_ROWS = 186, S1B = C1_ROWS * C1_CH * 2;  // 7440
constexpr int C2_CH = 44, C2_ROWS = 96, S2B = C2_ROWS * C2_CH * 2;   // 8448
constexpr int S3B = 5776;        // per-sample c3 stride
constexpr int XB_STRIDE = 392;   // bf16 lidar stage: [2 zero][360 data][2 zero][28 slack]

constexpr int OFF_C3 = 0;
constexpr int SZ_C3 = NS * S3B;             // 92416
constexpr int OFF_C1 = OFF_C3 + SZ_C3;      // 92416
constexpr int SZ_C1 = NSG * S1B;            // 29760
constexpr int OFF_C2 = OFF_C1 + SZ_C1;      // 122176
constexpr int SZ_C2 = NSG * S2B + 512;      // 34304
constexpr int OFF_XB = OFF_C2 + SZ_C2;      // 156480
constexpr int SZ_XB = NSG * XB_STRIDE * 2;  // 3136
constexpr int OFF_PAR = OFF_XB + SZ_XB;     // 159616 ; f32: b1[16] b2[32] b3[64] fcb[64]
constexpr int SMEM_BYTES = OFF_PAR + 704;   // 160320
static_assert(SMEM_BYTES <= 163840, "LDS over budget");

// aliases (region liveness verified per phase)
constexpr int OFF_STATE = OFF_C1;                    // [16][68] f32
constexpr int OFF_SBF = OFF_C1 + 16 * 68 * 4;        // [16][104] bf16 (state+const+pad)
constexpr int OFF_FCRED = OFF_C2;                    // [4][4][16][17] f32
constexpr int OFF_Y = OFF_C2;                        // [3][16][84] f32 (aliases red, after)

// workspace layout (bytes)
constexpr size_t WSO_FCW = 0;                           // [64][2880] bf16, m'=t*64+o
constexpr size_t WSO_W2F = WSO_FCW + 64 * FCIN * 2;     // 368640: [3][32][32] bf16
constexpr size_t WSO_W3F = WSO_W2F + 3 * 32 * 32 * 2;   // 374784: [5][64][32] bf16
constexpr size_t WSO_UB  = WSO_W3F + 5 * 64 * 32 * 2;   // 395264: [3][80][96] bf16 sym-folded
constexpr size_t WSO_W1F = WSO_UB + 3 * 80 * 96 * 2;    // 441344: [16][32] bf16
constexpr size_t WS_NEED = WSO_W1F + 16 * 32 * 2;       // 442368

__device__ __forceinline__ short f2b(float f) {
    return (short)__builtin_bit_cast(unsigned short, __float2bfloat16(f));
}
__device__ __forceinline__ bf16x8 ld_frag8(const char* p) {   // 8B-aligned LDS, 2x ds_read_b64
    union { bf16x8 v; short4v h[2]; } u;
    u.h[0] = *(const short4v*)(p);
    u.h[1] = *(const short4v*)(p + 8);
    return u.v;
}
__device__ __forceinline__ int2 qab_of(int q) {
    float qf = (float)q;
    int a = (int)((135.0f - sqrtf(135.0f * 135.0f - 8.0f * qf)) * 0.5f);
    a = a < 0 ? 0 : (a > 66 ? 66 : a);
    while (a > 0 && (a * 67 - (a * (a - 1)) / 2) > q) --a;
    while (a < 66 && ((a + 1) * 67 - ((a + 1) * a) / 2) <= q) ++a;
    int b = a + (q - (a * 67 - (a * (a - 1)) / 2));
    return make_int2(a, b);
}

__global__ __launch_bounds__(256) void pre_convert(
    const float* __restrict__ fcw, const float* __restrict__ w2,
    const float* __restrict__ w3, const float* __restrict__ w1,
    const float* __restrict__ sw, char* __restrict__ ws) {
    int idx = blockIdx.x * 256 + threadIdx.x;
    if (idx < 64 * FCIN) {
        int j = idx / FCIN, mp = idx % FCIN;
        int o = mp & 63, t = mp >> 6;
        ((short*)(ws + WSO_FCW))[idx] = f2b(fcw[j * FCIN + o * 45 + t]);
    }
    if (idx < 3 * 32 * 32) {
        int p = idx >> 10, o = (idx >> 5) & 31, k32 = idx & 31;
        int kk = 2 * p + (k32 >> 4), ic = k32 & 15;
        float v = (kk < 5) ? w2[(o * 16 + ic) * 5 + kk] : 0.f;
        ((short*)(ws + WSO_W2F))[idx] = f2b(v);
    }
    if (idx < 5 * 64 * 32) {
        int kk = idx >> 11, o = (idx >> 5) & 63, ic = idx & 31;
        ((short*)(ws + WSO_W3F))[idx] = f2b(w3[(o * 32 + ic) * 5 + kk]);
    }
    if (idx < 3 * 80 * 96) {   // symmetric-folded quad+linear+const matrix
        int r = idx / (80 * 96), rem = idx % (80 * 96), nn = rem / 96, kk = rem % 96;
        float v = 0.f;
        if (nn < 68 && kk < 68) {
            if (nn == 67 && kk == 67) v = sw[r * LIB];
            else if (nn == 67) v = 0.5f * sw[r * LIB + 1 + kk];
            else if (kk == 67) v = 0.5f * sw[r * LIB + 1 + nn];
            else {
                int a = nn < kk ? nn : kk, b = nn < kk ? kk : nn;
                int q = a * 67 - (a * (a - 1)) / 2 + (b - a);
                v = sw[r * LIB + 68 + q];
                if (nn != kk) v *= 0.5f;
            }
        }
        ((short*)(ws + WSO_UB))[idx] = f2b(v);
    }
    if (idx < 512) {           // conv1 A-fragment [16 o][32 k], taps 0..4 valid
        int o = idx >> 5, k = idx & 31;
        ((short*)(ws + WSO_W1F))[idx] = (k < 5) ? f2b(w1[o * 5 + k]) : (short)0;
    }
}

__global__ __launch_bounds__(NT, 4) void sindy_mfma(
    const float* __restrict__ lidar, const float* __restrict__ odom,
    const float* __restrict__ w1, const float* __restrict__ b1,
    const float* __restrict__ w2, const float* __restrict__ b2,
    const float* __restrict__ w3, const float* __restrict__ b3,
    const float* __restrict__ fcw, const float* __restrict__ fcb,
    const float* __restrict__ sw, const char* __restrict__ ws,
    float* __restrict__ out)
{
    __shared__ char smem[SMEM_BYTES];
    const int tid = threadIdx.x;
    const int wv = tid >> 6, lane = tid & 63;
    const int lr = lane & 15, lg = lane >> 4;
    const long blk = blockIdx.x;
    float* par = (float*)(smem + OFF_PAR);
    short* xb = (short*)(smem + OFF_XB);

    // ---- wave roles (constant all groups) ----
    const int sW = wv & 3;              // sample-in-group
    const int qW = wv >> 2;             // 0..3
    const int o0_2 = (qW >> 1) * 16;    // conv2 o-tile
    const int o0_3 = qW * 16;           // conv3 o-tile

    // ---- fc wave roles (needed early for prefetch) ----
    const int jt_fc = wv & 3, kq_fc = wv >> 2, j0_fc = jt_fc * 16;
    const short* fb = ws ? (const short*)(ws + WSO_FCW) + (long)(j0_fc + lr) * FCIN : nullptr;
    auto loadB = [&](int kt) -> bf16x8 {
        int k = kt * 32 + lg * 8;
        if (fb) return *(const bf16x8*)(fb + k);
        bf16x8 bv;
        #pragma unroll
        for (int e = 0; e < 8; e++) {
            int mp = k + e, o = mp & 63, t = mp >> 6;
            bv[e] = f2b(fcw[(long)(j0_fc + lr) * FCIN + o * 45 + t]);
        }
        return bv;
    };
    bf16x8 bvA, bvB;   // fc B prefetch registers (filled in last conv phase)

    // ---- hoisted weight fragments ----
    bf16x8 af1, af2[3], af3[5];
    if (ws) {
        af1 = *(const bf16x8*)(ws + WSO_W1F + (lr * 32 + lg * 8) * 2);
        #pragma unroll
        for (int p = 0; p < 3; p++)
            af2[p] = *(const bf16x8*)(ws + WSO_W2F + ((p * 32 + o0_2 + lr) * 32 + lg * 8) * 2);
        #pragma unroll
        for (int kk = 0; kk < 5; kk++)
            af3[kk] = *(const bf16x8*)(ws + WSO_W3F + ((kk * 64 + o0_3 + lr) * 32 + lg * 8) * 2);
    } else {
        #pragma unroll
        for (int e = 0; e < 8; e++) { int k = lg * 8 + e; af1[e] = (k < 5) ? f2b(w1[lr * 5 + k]) : (short)0; }
        #pragma unroll
        for (int p = 0; p < 3; p++)
            #pragma unroll
            for (int e = 0; e < 8; e++) {
                int k32 = lg * 8 + e, kk = 2 * p + (k32 >> 4), ic = k32 & 15;
                af2[p][e] = (kk < 5) ? f2b(w2[((o0_2 + lr) * 16 + ic) * 5 + kk]) : (short)0;
            }
        #pragma unroll
        for (int kk = 0; kk < 5; kk++)
            #pragma unroll
            for (int e = 0; e < 8; e++)
                af3[kk][e] = f2b(w3[((o0_3 + lr) * 32 + lg * 8 + e) * 5 + kk]);
    }

    // ---- bf16 lidar staging helper ----
    auto stage_xb = [&](int g) {
        float4v v = ((const float4v*)(lidar + (blk * NS + g * NSG) * L0))[tid];
        int si = tid / 90, c = tid % 90;
        short* dst = xb + si * XB_STRIDE + 2 + 4 * c;
        int p0 = (int)(unsigned short)f2b(v[0]) | ((int)(unsigned short)f2b(v[1]) << 16);
        int p1 = (int)(unsigned short)f2b(v[2]) | ((int)(unsigned short)f2b(v[3]) << 16);
        *(int*)(dst) = p0;
        *(int*)(dst + 2) = p1;
    };

    // ================= P0 =================
    if (tid < 16) par[tid] = b1[tid];
    else if (tid < 48) par[16 + tid - 16] = b2[tid - 16];
    else if (tid < 112) par[48 + tid - 48] = b3[tid - 48];
    else if (tid < 176) par[112 + tid - 112] = fcb[tid - 112];
    else if (tid < 184) {               // xb border zeros
        int s = (tid - 176) >> 1, h = (tid - 176) & 1;
        ((int*)xb)[s * (XB_STRIDE / 2) + (h ? 181 : 0)] = 0;
    }
    if (tid >= 448 && tid < 608) {      // c1 borders
        int i = tid - 448, slot = i / 40, r = i % 40;
        const int rows[4] = {2, 3, 184, 185};
        *(int*)(smem + OFF_C1 + slot * S1B + rows[r / 10] * (C1_CH * 2) + (r % 10) * 4) = 0;
    }
    if (tid >= 608 && tid < 960) {      // c2 borders
        int i = tid - 608, slot = i / 88, r = i % 88;
        const int rows[4] = {2, 3, 94, 95};
        *(int*)(smem + OFF_C2 + slot * S2B + rows[r / 22] * (C2_CH * 2) + (r % 22) * 4) = 0;
    }
    if (tid < 360) stage_xb(0);
    __syncthreads();

    // ---- hoisted biases ----
    float bia1_[4], bia2_[4], bia3_[4];
    #pragma unroll
    for (int r = 0; r < 4; r++) {
        bia1_[r] = par[lg * 4 + r];
        bia2_[r] = par[16 + o0_2 + lg * 4 + r];
        bia3_[r] = par[48 + o0_3 + lg * 4 + r];
    }

    // ---- conv1 via MFMA ----
    auto conv1_body = [&]() {
        const short* xs = xb + sW * XB_STRIDE;
        char* c1s = smem + OFF_C1 + sW * S1B;
        #pragma unroll
        for (int i = 0; i < 3; ++i) {
            const int t = (qW * 3 + i) * 16 + lr;
            bf16x8 bv = {0, 0, 0, 0, 0, 0, 0, 0};
            if (lg == 0) {
                const short* xp = xs + 2 * t;
                int d0 = *(const int*)(xp);
                int d1 = *(const int*)(xp + 2);
                bv[0] = (short)(d0 & 0xffff); bv[1] = (short)(d0 >> 16);
                bv[2] = (short)(d1 & 0xffff); bv[3] = (short)(d1 >> 16);
                bv[4] = xp[4];
            }
            f32x4 acc = {0.f, 0.f, 0.f, 0.f};
            acc = __builtin_amdgcn_mfma_f32_16x16x32_bf16(af1, bv, acc, 0, 0, 0);
            if (t < 180) {
                short4v pk = { f2b(fmaxf(acc[0] + bia1_[0], 0.f)), f2b(fmaxf(acc[1] + bia1_[1], 0.f)),
                               f2b(fmaxf(acc[2] + bia1_[2], 0.f)), f2b(fmaxf(acc[3] + bia1_[3], 0.f)) };
                *(short4v*)(c1s + (t + 4) * (C1_CH * 2) + lg * 8) = pk;
            }
        }
    };

    conv1_body();                        // C1(g=0)
    __syncthreads();

    // ================= conv groups: {C2(g)+stage | C3(g)+C1(g+1)} =================
    for (int g = 0; g < NGRP; ++g) {
        // ---- C2: hoisted base, all reads at compile-time offsets ----
        {
            const int orow = o0_2 + lg * 4;
            const int kkp = lane >> 5, i0 = (lg & 1) * 8;
            const char* bp = smem + OFF_C1 + sW * S1B
                           + (2 * lr + kkp + 2) * (C1_CH * 2) + i0 * 2
                           + (qW & 1) * 3840;            // 3*16*2*(C1_CH*2)
            char* c2s = smem + OFF_C2 + sW * S2B;
            const bool stg = (g < NGRP - 1) && (tid < 360);
            float4v lv;
            if (stg) lv = ((const float4v*)(lidar + (blk * NS + (g + 1) * NSG) * L0))[tid];
            #pragma unroll
            for (int i = 0; i < 3; ++i) {
                f32x4 acc = {0.f, 0.f, 0.f, 0.f};
                #pragma unroll
                for (int p = 0; p < 3; p++) {
                    bf16x8 bf = ld_frag8(bp + i * 1280 + p * 80);   // i*16*80 + p*2*40
                    acc = __builtin_amdgcn_mfma_f32_16x16x32_bf16(af2[p], bf, acc, 0, 0, 0);
                }
                const int tw = ((qW & 1) * 3 + i) * 16 + lr;
                if (tw < L2n) {
                    short4v pk = { f2b(fmaxf(acc[0] + bia2_[0], 0.f)), f2b(fmaxf(acc[1] + bia2_[1], 0.f)),
                                   f2b(fmaxf(acc[2] + bia2_[2], 0.f)), f2b(fmaxf(acc[3] + bia2_[3], 0.f)) };
                    *(short4v*)(c2s + (tw + 4) * (C2_CH * 2) + orow * 2) = pk;
                }
            }
            if (stg) {
                int si = tid / 90, c = tid % 90;
                short* dst = xb + si * XB_STRIDE + 2 + 4 * c;
                int p0 = (int)(unsigned short)f2b(lv[0]) | ((int)(unsigned short)f2b(lv[1]) << 16);
                int p1 = (int)(unsigned short)f2b(lv[2]) | ((int)(unsigned short)f2b(lv[3]) << 16);
                *(int*)(dst) = p0;
                *(int*)(dst + 2) = p1;
            }
        }
        __syncthreads();

        // ---- C3(g) + C1(g+1) : hoisted base, compile-time offsets ----
        {
            const int orow = o0_3 + lg * 4;
            const char* bp2 = smem + OFF_C2 + sW * S2B
                            + (2 * lr + 2) * (C2_CH * 2) + lg * 16;
            char* c3s = smem + OFF_C3 + (g * NSG + sW) * S3B;
            #pragma unroll
            for (int tt = 0; tt < 3; ++tt) {
                f32x4 acc = {0.f, 0.f, 0.f, 0.f};
                #pragma unroll
                for (int kk = 0; kk < 5; kk++) {
                    bf16x8 bf = ld_frag8(bp2 + tt * 2816 + kk * 88);   // tt*32*88 + kk*88
                    acc = __builtin_amdgcn_mfma_f32_16x16x32_bf16(af3[kk], bf, acc, 0, 0, 0);
                }
                const int tw = tt * 16 + lr;
                if (tw < L3n) {
                    short4v pk = { f2b(fmaxf(acc[0] + bia3_[0], 0.f)), f2b(fmaxf(acc[1] + bia3_[1], 0.f)),
                                   f2b(fmaxf(acc[2] + bia3_[2], 0.f)), f2b(fmaxf(acc[3] + bia3_[3], 0.f)) };
                    int byteoff = (tw * 64 + orow) * 2;
                    byteoff ^= (tw & 7) << 4;
                    *(short4v*)(c3s + byteoff) = pk;
                }
            }
            if (g < NGRP - 1) conv1_body();
            else { bvA = loadB(kq_fc); bvB = loadB(kq_fc + 4); }   // fc B prefetch across barrier
        }
        __syncthreads();
    }

    // ================= FC: M=16, N=64, K=2880 ; wave = (j-tile, k-quarter) =================
    {
        const int nI = (kq_fc < 2) ? 23 : 22;
        const char* abase = smem + OFF_C3 + lr * S3B;
        auto loadA = [&](int kt) -> bf16x8 {
            int k = kt * 32 + lg * 8;
            int bo = (k * 2) ^ (((k >> 6) & 7) << 4);
            return *(const bf16x8*)(abase + bo);
        };
        f32x4 accA = {0.f, 0.f, 0.f, 0.f}, accB = {0.f, 0.f, 0.f, 0.f};
        int kt = kq_fc;
        bf16x8 bv0 = bvA, bv1 = bvB;
        int i = 0;
        for (; i + 1 < nI; i += 2) {
            bf16x8 cur0 = bv0; bv0 = bv1;
            if (i + 2 < nI) bv1 = loadB(kt + 8);
            accA = __builtin_amdgcn_mfma_f32_16x16x32_bf16(loadA(kt), cur0, accA, 0, 0, 0);
            kt += 4;
            bf16x8 cur1 = bv0; bv0 = bv1;
            if (i + 3 < nI) bv1 = loadB(kt + 8);
            accB = __builtin_amdgcn_mfma_f32_16x16x32_bf16(loadA(kt), cur1, accB, 0, 0, 0);
            kt += 4;
        }
        if (i < nI)
            accA = __builtin_amdgcn_mfma_f32_16x16x32_bf16(loadA(kt), bv0, accA, 0, 0, 0);
        f32x4 acc = accA + accB;
        float* red = (float*)(smem + OFF_FCRED);
        #pragma unroll
        for (int r = 0; r < 4; r++)
            red[((jt_fc * 4 + kq_fc) * 16 + lg * 4 + r) * 17 + lr] = acc[r];
    }
    __syncthreads();

    // ================= fc-reduce (wave = sample) + trig partials =================
    const int s = wv;
    const long n = blk * NS + s;
    float* red = (float*)(smem + OFF_FCRED);
    float* strow = (float*)(smem + OFF_STATE) + s * 68;
    short* sbrow = (short*)(smem + OFF_SBF) + s * 104;
    float ts0, ts1, ts2;
    {
        int jt = lane >> 4, col = lane & 15;
        float v = red[((jt * 4 + 0) * 16 + s) * 17 + col]
                + red[((jt * 4 + 1) * 16 + s) * 17 + col]
                + red[((jt * 4 + 2) * 16 + s) * 17 + col]
                + red[((jt * 4 + 3) * 16 + s) * 17 + col]
                + par[112 + lane];
        strow[lane] = v;
        if (ws) sbrow[lane] = f2b(v);
        float sn = __sinf(v), cs = __cosf(v);
        ts0 = sw[2346 + lane] * sn + sw[2413 + lane] * cs;
        ts1 = sw[LIB + 2346 + lane] * sn + sw[LIB + 2413 + lane] * cs;
        ts2 = sw[2 * LIB + 2346 + lane] * sn + sw[2 * LIB + 2413 + lane] * cs;
        if (lane < 3) {
            float ov = odom[n * 3 + lane];
            strow[64 + lane] = ov;
            if (ws) sbrow[64 + lane] = f2b(ov);
            float sn2 = __sinf(ov), cs2 = __cosf(ov);
            int j2 = 64 + lane;
            ts0 += sw[2346 + j2] * sn2 + sw[2413 + j2] * cs2;
            ts1 += sw[LIB + 2346 + j2] * sn2 + sw[LIB + 2413 + j2] * cs2;
            ts2 += sw[2 * LIB + 2346 + j2] * sn2 + sw[2 * LIB + 2413 + j2] * cs2;
        }
        if (ws) {
            if (lane == 3) sbrow[67] = (short)0x3F80;            // 1.0 bf16 (const column)
            if (lane >= 4 && lane < 40) sbrow[64 + lane] = 0;    // pad 68..103
        }
    }

    if (ws) {
        __syncthreads();
        // ---- quad GEMM: Y_r = S * Ub_r^T ; 15 waves = (r, n-tile) ----
        if (wv < 15) {
            const int r = wv / 5, nt = wv % 5;
            const char* ubp = ws + WSO_UB + (size_t)(r * 80 + nt * 16 + lr) * 96 * 2;
            const char* sb = smem + OFF_SBF;
            f32x4 acc = {0.f, 0.f, 0.f, 0.f};
            #pragma unroll
            for (int kt = 0; kt < 3; ++kt) {
                bf16x8 av = ld_frag8(sb + lr * 208 + (kt * 32 + lg * 8) * 2);
                bf16x8 bv = *(const bf16x8*)(ubp + (kt * 32 + lg * 8) * 2);
                acc = __builtin_amdgcn_mfma_f32_16x16x32_bf16(av, bv, acc, 0, 0, 0);
            }
            float* Y = (float*)(smem + OFF_Y);
            #pragma unroll
            for (int rr = 0; rr < 4; ++rr)
                Y[(r * 16 + lg * 4 + rr) * 84 + nt * 16 + lr] = acc[rr];
        }
        __syncthreads();
        // ---- dot(S, Y_r) + trig partials -> out ----
        const float* Y = (const float*)(smem + OFF_Y);
        float sj = strow[lane];
        float d0 = Y[(0 * 16 + s) * 84 + lane] * sj + ts0;
        float d1 = Y[(1 * 16 + s) * 84 + lane] * sj + ts1;
        float d2 = Y[(2 * 16 + s) * 84 + lane] * sj + ts2;
        if (lane < 4) {
            int j = 64 + lane;
            float sj2 = (lane < 3) ? strow[j] : 1.0f;
            d0 += Y[(0 * 16 + s) * 84 + j] * sj2;
            d1 += Y[(1 * 16 + s) * 84 + j] * sj2;
            d2 += Y[(2 * 16 + s) * 84 + j] * sj2;
        }
        #pragma unroll
        for (int off = 32; off; off >>= 1) {
            d0 += __shfl_xor(d0, off, 64);
            d1 += __shfl_xor(d1, off, 64);
            d2 += __shfl_xor(d2, off, 64);
        }
        if (lane == 0) {
            out[n * 3 + 0] = strow[64] + 0.1f * d0;
            out[n * 3 + 1] = strow[65] + 0.1f * d1;
            out[n * 3 + 2] = strow[66] + 0.1f * d2;
        }
    } else {
        // ---- fallback scalar tail (no ws) ----
        for (int i2 = lane; i2 < SD; i2 += 64) {
            float sv = strow[i2];
            ts0 += sw[1 + i2] * sv; ts1 += sw[LIB + 1 + i2] * sv; ts2 += sw[2 * LIB + 1 + i2] * sv;
        }
        if (lane == 0) { ts0 += sw[0]; ts1 += sw[LIB]; ts2 += sw[2 * LIB]; }
        for (int q = lane; q < NQ; q += 64) {
            int2 ab = qab_of(q);
            float p = strow[ab.x] * strow[ab.y];
            ts0 += sw[68 + q] * p; ts1 += sw[LIB + 68 + q] * p; ts2 += sw[2 * LIB + 68 + q] * p;
        }
        #pragma unroll
        for (int off = 32; off; off >>= 1) {
            ts0 += __shfl_xor(ts0, off, 64);
            ts1 += __shfl_xor(ts1, off, 64);
            ts2 += __shfl_xor(ts2, off, 64);
        }
        if (lane == 0) {
            out[n * 3 + 0] = strow[64] + 0.1f * ts0;
            out[n * 3 + 1] = strow[65] + 0.1f * ts1;
            out[n * 3 + 2] = strow[66] + 0.1f * ts2;
        }
    }
}

extern "C" void kernel_launch(void* const* d_in, const int* in_sizes, int n_in,
                              void* d_out, int out_size, void* d_ws, size_t ws_size,
                              hipStream_t stream) {
    const float* lidar = (const float*)d_in[0];
    const float* odom  = (const float*)d_in[1];
    const float* w1    = (const float*)d_in[2];
    const float* b1    = (const float*)d_in[3];
    const float* w2    = (const float*)d_in[4];
    const float* b2    = (const float*)d_in[5];
    const float* w3    = (const float*)d_in[6];
    const float* b3    = (const float*)d_in[7];
    const float* fcw   = (const float*)d_in[8];
    const float* fcb   = (const float*)d_in[9];
    const float* sw    = (const float*)d_in[10];
    float* out = (float*)d_out;

    int B = in_sizes[0] / L0;          // 32768
    int blocks = B / NS;               // 2048

    char* ws = nullptr;
    if (ws_size >= WS_NEED) {
        ws = (char*)d_ws;
        pre_convert<<<(64 * FCIN + 255) / 256, 256, 0, stream>>>(fcw, w2, w3, w1, sw, ws);
    }
    sindy_mfma<<<blocks, NT, 0, stream>>>(lidar, odom, w1, b1, w2, b2, w3, b3,
                                          fcw, fcb, sw, ws, out);
}